// Round 4
// baseline (369.468 us; speedup 1.0000x reference)
//
#include <hip/hip_runtime.h>

// data: [4, 3, 1024, 1024] fp32; NX=64, scale=16, ny=64, N=4096, p=15
// out = concat(A[4,4096,4096], data) flat fp32
//
// A is banded: row n has nonzeros only at cols n-64, n-1, n+1, n+64.
// One block per A-row. STORE-FIRST / PATCH-LATE:
//   pass 1: nt-store zeros to all quads that cannot contain a band column
//           (no data dependency -> write pipe saturates from cycle 0,
//            edge-gather latency hides underneath)
//   pass 2: after the 4 waves compute the row's incident edge values
//           (bit-identical lane layout + butterfly across both incident
//            rows -> exact symmetry), store the <=4 band quads patched.
// Each A byte is written exactly once; no memset anywhere.
// Harness's own ~197us re-poison fill is outside our control; our kernel
// was ~148us (absent from duration-sorted top-5 which starts at 196us).
#define BB 4
#define CC 3
#define HH 1024
#define WW 1024
#define NXG 64
#define SCALE 16
#define PP 15
#define NNODE 4096

typedef float floatx4 __attribute__((ext_vector_type(4)));

static const long long A_ELEMS    = (long long)BB * NNODE * NNODE;   // 67,108,864
static const long long DATA_ELEMS = (long long)BB * CC * HH * WW;    // 12,582,912

#define COPY_BLOCKS 512
#define ROW_BLOCKS  (BB * NNODE)   // 16384 row blocks, one per (b, n)

__global__ __launch_bounds__(256) void fused_band_fill(const float* __restrict__ data,
                                                       float* __restrict__ out) {
    if (blockIdx.x >= ROW_BLOCKS) {
        // data -> out tail, launched after row blocks so A stores start first.
        long long i = (long long)(blockIdx.x - ROW_BLOCKS) * 256 + threadIdx.x;
        const long long stride = (long long)COPY_BLOCKS * 256;
        const floatx4* __restrict__ src = (const floatx4*)data;
        floatx4* dst = (floatx4*)(out + A_ELEMS);
        const long long nvec = DATA_ELEMS / 4;
        for (; i < nvec; i += stride) {
            floatx4 v = src[i];
            __builtin_nontemporal_store(v, dst + i);
        }
        return;
    }

    const int rb = blockIdx.x;                 // 0..16383
    const int b  = rb >> 12;                   // batch
    const int n  = rb & (NNODE - 1);           // node/row id
    const int y  = n >> 6;
    const int x  = n & 63;

    // Band columns of row n; sentinel -1 (also -1>>2 == -1, never a quad id).
    const int c_up = (y > 0)  ? n - NXG : -1;
    const int c_dn = (y < 63) ? n + NXG : -1;
    const int c_lf = (x > 0)  ? n - 1   : -1;
    const int c_rt = (x < 63) ? n + 1   : -1;

    float* rowp = out + ((long long)b * NNODE + n) * NNODE;

    // ---- pass 1: dependency-free zero stream over non-band quads ----
    bool band[4];
    #pragma unroll
    for (int k = 0; k < 4; ++k) {
        const int t = (int)threadIdx.x + (k << 8);        // quad id 0..1023
        const bool isb = ((c_up >> 2) == t) | ((c_dn >> 2) == t) |
                         ((c_lf >> 2) == t) | ((c_rt >> 2) == t);
        band[k] = isb;
        if (!isb) {
            floatx4 z = {0.f, 0.f, 0.f, 0.f};
            __builtin_nontemporal_store(z, (floatx4*)(rowp + (t << 2)));
        }
    }

    // ---- edge compute (unchanged math; gathers overlap pass-1 stores) ----
    const int w    = threadIdx.x >> 6;         // wave: 0=up 1=down 2=left 3=right
    const int lane = threadIdx.x & 63;
    const int r    = lane >> 2;                // patch row 0..15 (15 inactive)
    const int q    = lane & 3;                 // float4 quad in the 16-wide cell

    bool valid; int gy, gx; long long delta;
    switch (w) {
        case 0:  valid = (y > 0);  gy = y - 1; gx = x;     delta = (long long)SCALE * WW; break;
        case 1:  valid = (y < 63); gy = y;     gx = x;     delta = (long long)SCALE * WW; break;
        case 2:  valid = (x > 0);  gy = y;     gx = x - 1; delta = SCALE;                 break;
        default: valid = (x < 63); gy = y;     gx = x;     delta = SCALE;                 break;
    }

    float s = 0.f;
    if (valid && r < PP) {
        const float* p0 = data + (((long long)(b * CC)) * HH + (long long)(gy * SCALE + r)) * WW
                               + gx * SCALE + q * 4;
        #pragma unroll
        for (int c = 0; c < CC; ++c) {
            const float* p = p0 + (long long)c * HH * WW;
            const floatx4 a  = *(const floatx4*)p;
            const floatx4 nb = *(const floatx4*)(p + delta);
            float d = fabsf(nb.x - a.x) + fabsf(nb.y - a.y) + fabsf(nb.z - a.z);
            if (q != 3) d += fabsf(nb.w - a.w);   // col 15 excluded
            s += d;
        }
    }
    #pragma unroll
    for (int off = 32; off; off >>= 1) s += __shfl_down(s, off, 64);

    __shared__ float ev[4];
    if (lane == 0) ev[w] = s;
    __syncthreads();

    const float v_up = ev[0], v_dn = ev[1], v_lf = ev[2], v_rt = ev[3];

    // ---- pass 2: patch the <=4 band quads (each address stored once) ----
    #pragma unroll
    for (int k = 0; k < 4; ++k) {
        if (!band[k]) continue;
        const int cb = ((int)threadIdx.x + (k << 8)) << 2;   // col base of quad
        const int c0 = cb, c1 = cb + 1, c2 = cb + 2, c3 = cb + 3;
        floatx4 v;
        v.x = (c0 == c_up) ? v_up : (c0 == c_dn) ? v_dn : (c0 == c_lf) ? v_lf : (c0 == c_rt) ? v_rt : 0.f;
        v.y = (c1 == c_up) ? v_up : (c1 == c_dn) ? v_dn : (c1 == c_lf) ? v_lf : (c1 == c_rt) ? v_rt : 0.f;
        v.z = (c2 == c_up) ? v_up : (c2 == c_dn) ? v_dn : (c2 == c_lf) ? v_lf : (c2 == c_rt) ? v_rt : 0.f;
        v.w = (c3 == c_up) ? v_up : (c3 == c_dn) ? v_dn : (c3 == c_lf) ? v_lf : (c3 == c_rt) ? v_rt : 0.f;
        __builtin_nontemporal_store(v, (floatx4*)(rowp + cb));
    }
}

extern "C" void kernel_launch(void* const* d_in, const int* in_sizes, int n_in,
                              void* d_out, int out_size, void* d_ws, size_t ws_size,
                              hipStream_t stream) {
    const float* data = (const float*)d_in[0];
    float* out = (float*)d_out;
    fused_band_fill<<<ROW_BLOCKS + COPY_BLOCKS, 256, 0, stream>>>(data, out);
}

// Round 6
// 348.587 us; speedup vs baseline: 1.0599x; 1.0599x over previous
//
#include <hip/hip_runtime.h>

// data: [4, 3, 1024, 1024] fp32; NX=64, scale=16, ny=64, N=4096, p=15
// out = concat(A[4,4096,4096], data) flat fp32
//
// A is banded: row n has nonzeros only at cols n-64, n-1, n+1, n+64.
// Round-3 structure (best so far: 345us total, ~148us ours) with ONE change:
// PLAIN stores instead of nontemporal. Theory: nt 16B/lane granules bypass
// L2 coalescing and pay a full HBM burst each (4x write amplification --
// matches the poison fill's 4x WRITE_SIZE and our ~148us A-write time).
// Plain stores stream through L2 and drain as full lines.
// Round-4's store-first experiment regressed (+24us) and is reverted.
// (Resubmission: round 5 hit a GPU-acquisition timeout; kernel never ran.)
#define BB 4
#define CC 3
#define HH 1024
#define WW 1024
#define NXG 64
#define SCALE 16
#define PP 15
#define NNODE 4096

typedef float floatx4 __attribute__((ext_vector_type(4)));

static const long long A_ELEMS    = (long long)BB * NNODE * NNODE;   // 67,108,864
static const long long DATA_ELEMS = (long long)BB * CC * HH * WW;    // 12,582,912

#define COPY_BLOCKS 512
#define ROW_BLOCKS  (BB * NNODE)   // 16384 row blocks, one per (b, n)

__global__ __launch_bounds__(256) void fused_band_fill(const float* __restrict__ data,
                                                       float* __restrict__ out) {
    if (blockIdx.x < COPY_BLOCKS) {
        // data -> out tail. Plain loads keep data hot in L2/L3 for the
        // edge gathers; plain stores coalesce in L2.
        long long i = (long long)blockIdx.x * 256 + threadIdx.x;
        const long long stride = (long long)COPY_BLOCKS * 256;
        const floatx4* __restrict__ src = (const floatx4*)data;
        floatx4* dst = (floatx4*)(out + A_ELEMS);
        const long long nvec = DATA_ELEMS / 4;
        for (; i < nvec; i += stride) dst[i] = src[i];
        return;
    }

    const int rb = blockIdx.x - COPY_BLOCKS;   // 0..16383
    const int b  = rb >> 12;                   // batch
    const int n  = rb & (NNODE - 1);           // node/row id
    const int y  = n >> 6;
    const int x  = n & 63;

    const int w    = threadIdx.x >> 6;         // wave: 0=up 1=down 2=left 3=right
    const int lane = threadIdx.x & 63;
    const int r    = lane >> 2;                // patch row 0..15 (15 inactive)
    const int q    = lane & 3;                 // float4 quad in the 16-wide cell

    bool valid; int gy, gx; long long delta;
    switch (w) {
        case 0:  valid = (y > 0);  gy = y - 1; gx = x;     delta = (long long)SCALE * WW; break;
        case 1:  valid = (y < 63); gy = y;     gx = x;     delta = (long long)SCALE * WW; break;
        case 2:  valid = (x > 0);  gy = y;     gx = x - 1; delta = SCALE;                 break;
        default: valid = (x < 63); gy = y;     gx = x;     delta = SCALE;                 break;
    }

    // Edge computed redundantly by both incident rows, but with identical
    // lane layout and reduction order -> bit-identical, symmetry exact.
    float s = 0.f;
    if (valid && r < PP) {
        const float* p0 = data + (((long long)(b * CC)) * HH + (long long)(gy * SCALE + r)) * WW
                               + gx * SCALE + q * 4;
        #pragma unroll
        for (int c = 0; c < CC; ++c) {
            const float* p = p0 + (long long)c * HH * WW;
            const floatx4 a  = *(const floatx4*)p;
            const floatx4 nb = *(const floatx4*)(p + delta);
            float d = fabsf(nb.x - a.x) + fabsf(nb.y - a.y) + fabsf(nb.z - a.z);
            if (q != 3) d += fabsf(nb.w - a.w);   // col 15 excluded
            s += d;
        }
    }
    #pragma unroll
    for (int off = 32; off; off >>= 1) s += __shfl_down(s, off, 64);

    __shared__ float ev[4];
    if (lane == 0) ev[w] = s;
    __syncthreads();

    const float v_up = ev[0], v_dn = ev[1], v_lf = ev[2], v_rt = ev[3];
    // Sentinel -1 for nonexistent neighbors: never matches a col in [0,4096).
    const int c_up = (y > 0)  ? n - NXG : -1;
    const int c_dn = (y < 63) ? n + NXG : -1;
    const int c_lf = (x > 0)  ? n - 1   : -1;
    const int c_rt = (x < 63) ? n + 1   : -1;

    float* rowp = out + ((long long)b * NNODE + n) * NNODE;
    #pragma unroll
    for (int k = 0; k < 4; ++k) {
        const int cb = (int)(threadIdx.x + k * 256) << 2;   // col base of this quad
        const int c0 = cb, c1 = cb + 1, c2 = cb + 2, c3 = cb + 3;
        floatx4 v;
        v.x = (c0 == c_up) ? v_up : (c0 == c_dn) ? v_dn : (c0 == c_lf) ? v_lf : (c0 == c_rt) ? v_rt : 0.f;
        v.y = (c1 == c_up) ? v_up : (c1 == c_dn) ? v_dn : (c1 == c_lf) ? v_lf : (c1 == c_rt) ? v_rt : 0.f;
        v.z = (c2 == c_up) ? v_up : (c2 == c_dn) ? v_dn : (c2 == c_lf) ? v_lf : (c2 == c_rt) ? v_rt : 0.f;
        v.w = (c3 == c_up) ? v_up : (c3 == c_dn) ? v_dn : (c3 == c_lf) ? v_lf : (c3 == c_rt) ? v_rt : 0.f;
        *(floatx4*)(rowp + cb) = v;
    }
}

extern "C" void kernel_launch(void* const* d_in, const int* in_sizes, int n_in,
                              void* d_out, int out_size, void* d_ws, size_t ws_size,
                              hipStream_t stream) {
    const float* data = (const float*)d_in[0];
    float* out = (float*)d_out;
    fused_band_fill<<<COPY_BLOCKS + ROW_BLOCKS, 256, 0, stream>>>(data, out);
}